// Round 2
// baseline (348.688 us; speedup 1.0000x reference)
//
#include <hip/hip_runtime.h>
#include <hip/hip_bf16.h>

typedef __bf16 bf16_t;
typedef __bf16 bf16x4 __attribute__((ext_vector_type(4)));
typedef __bf16 bf16x8 __attribute__((ext_vector_type(8)));
typedef float  f32x4  __attribute__((ext_vector_type(4)));

#define XP 264          // sX row pitch (elems); 528 B rows
#define QP 72           // q/k row pitch (64 cols + 8 pad)
#define VP 72
#define PP 72
#define SCL 0.09016844f // (1/16) * log2(e): softmax scale folded into exp2

__device__ inline bf16x8 cvt8(f32x4 a, f32x4 b) {
    bf16x8 r;
    r[0]=(bf16_t)a[0]; r[1]=(bf16_t)a[1]; r[2]=(bf16_t)a[2]; r[3]=(bf16_t)a[3];
    r[4]=(bf16_t)b[0]; r[5]=(bf16_t)b[1]; r[6]=(bf16_t)b[2]; r[7]=(bf16_t)b[3];
    return r;
}

// Prep: W{q,k,v} fp32 [256x256] -> bf16 into ws ([3][256][256]). 96 blocks x 256 thr.
__global__ __launch_bounds__(256)
void wcvt_kernel(const float* __restrict__ Wq, const float* __restrict__ Wk,
                 const float* __restrict__ Wv, bf16_t* __restrict__ o)
{
    int e = (blockIdx.x * 256 + threadIdx.x) * 8;
    const float* src = (e < 65536) ? (Wq + e)
                     : (e < 131072 ? (Wk + (e - 65536)) : (Wv + (e - 131072)));
    f32x4 f0 = *(const f32x4*)src;
    f32x4 f1 = *(const f32x4*)(src + 4);
    *(bf16x8*)(o + e) = cvt8(f0, f1);
}

// One block = one WINDOW, 8 waves (512 thr), loops over 4 head-pair groups.
// LDS 53520 B -> 2 blocks/CU = 16 waves/CU; 8 blocks/CU / 2 slots = 0 tail.
// Proj: wave = (dim-tile dt = wv&3, token-half th = wv>>2). QKV fused: each
// X-fragment ds_read feeds 3 MFMAs. Q/K computed as mfma(W,X) -> D=[dim][tok]
// so 4 acc elems = 4 consecutive dims = one b64 store into sQ[tok][dim];
// V as mfma(X,W) -> b64 store into sVT[dim][tok]. Attn: wave = (token-tile
// tt = wv&3, head-slice hs = wv>>2); S^T = mfma(K,Q) so 4 acc elems = 4
// consecutive k-tokens = one b64 store into wave-private sP[q][k].
// sP overlays sX elems [0,9216) (rows 0..34); restored from xreg between groups.
// Proj A-reads of virtual token rows 49..63 read into sQ region (garbage/NaN);
// they only affect outputs with t>=49 (never stored); sVT cols >=49 and sP
// cols >=49 are forced to exact 0 so garbage cannot cross rows via PV/ones-MFMA.
__global__ __launch_bounds__(512, 4)
void swin_win_attn(const float* __restrict__ x,
                   const bf16_t* __restrict__ Wb,      // ws: [3][256][256] bf16
                   const float* __restrict__ bq, const float* __restrict__ bk,
                   const float* __restrict__ bv,
                   float* __restrict__ out)
{
    __shared__ __attribute__((aligned(16))) bf16_t smem[49 * XP + 2 * 64 * QP + 64 * VP];
    bf16_t* sX  = smem;                 // [49][XP]; elems [0,9216) reused as 8x sP
    bf16_t* sQ  = smem + 49 * XP;       // [64 tok][QP]
    bf16_t* sK  = sQ + 64 * QP;         // [64 tok][QP]
    bf16_t* sVT = sK + 64 * QP;         // [64 dim][VP tok]

    const int tid  = threadIdx.x;       // 0..511
    const int wv   = tid >> 6;          // 0..7
    const int lane = tid & 63;
    const int l15  = lane & 15;
    const int quad = lane >> 4;

    const int win = blockIdx.x;                      // 0..2047
    const int b  = win >> 6;
    const int w  = win & 63;
    const int wy = w >> 3;
    const int wx = w & 7;
    const float* xw = x + (((b * 56) + wy * 7) * 56 + wx * 7) * 256;

    // ---- stage x (fp32 -> bf16): issue ALL loads, then all LDS writes ----
    f32x4 la[4], lb[4];
    #pragma unroll
    for (int k = 0; k < 3; ++k) {
        int idx = k * 512 + tid, row = idx >> 5, cv = idx & 31;   // rows 0..47
        int ty = row / 7, tx = row - ty * 7;
        const float* src = xw + (ty * 56 + tx) * 256 + cv * 8;
        la[k] = *(const f32x4*)src;
        lb[k] = *(const f32x4*)(src + 4);
    }
    if (tid < 32) {
        const float* src = xw + (6 * 56 + 6) * 256 + tid * 8;     // row 48
        la[3] = *(const f32x4*)src;
        lb[3] = *(const f32x4*)(src + 4);
    }
    bf16x8 xreg[3];     // persistent copy of rows 0..47 slice owned by this thread
    #pragma unroll
    for (int k = 0; k < 3; ++k) {
        int idx = k * 512 + tid, row = idx >> 5, cv = idx & 31;
        bf16x8 c = cvt8(la[k], lb[k]);
        xreg[k] = c;
        *(bf16x8*)&sX[row * XP + cv * 8] = c;
    }
    if (tid < 32)
        *(bf16x8*)&sX[48 * XP + tid * 8] = cvt8(la[3], lb[3]);

    const int dt = wv & 3;    // proj: dim-tile   | attn: token-tile
    const int th = wv >> 2;   // proj: token-half | attn: head-slice
    const bf16_t* wb0 = Wb + (dt * 16 + l15) * 256 + quad * 8;

    bf16x8 vone;
    #pragma unroll
    for (int j = 0; j < 8; ++j) vone[j] = (bf16_t)1.0f;

    __syncthreads();

    #pragma unroll 1
    for (int g = 0; g < 4; ++g) {
        // ---- fused QKV projection ----
        const bf16_t* wbg = wb0 + g * 64 * 256;
        f32x4 qb4 = *(const f32x4*)&bq[g * 64 + dt * 16 + quad * 4];
        f32x4 kb4 = *(const f32x4*)&bk[g * 64 + dt * 16 + quad * 4];
        float bvs = bv[g * 64 + dt * 16 + l15];

        f32x4 accq[2], acck[2], accv[2];
        #pragma unroll
        for (int m = 0; m < 2; ++m) {
            accq[m] = f32x4{0.f,0.f,0.f,0.f};
            acck[m] = f32x4{0.f,0.f,0.f,0.f};
            accv[m] = f32x4{0.f,0.f,0.f,0.f};
        }
        #pragma unroll
        for (int half = 0; half < 2; ++half) {
            bf16x8 wqf[4], wkf[4], wvf[4];
            #pragma unroll
            for (int ks = 0; ks < 4; ++ks) {
                int kk = half * 4 + ks;
                wqf[ks] = *(const bf16x8*)(wbg + kk * 32);
                wkf[ks] = *(const bf16x8*)(wbg + 65536 + kk * 32);
                wvf[ks] = *(const bf16x8*)(wbg + 131072 + kk * 32);
            }
            #pragma unroll
            for (int m = 0; m < 2; ++m) {
                int T = th * 2 + m;
                #pragma unroll
                for (int ks = 0; ks < 4; ++ks) {
                    int kk = half * 4 + ks;
                    bf16x8 a = *(const bf16x8*)&sX[(T * 16 + l15) * XP + kk * 32 + quad * 8];
                    accq[m] = __builtin_amdgcn_mfma_f32_16x16x32_bf16(wqf[ks], a, accq[m], 0, 0, 0);
                    acck[m] = __builtin_amdgcn_mfma_f32_16x16x32_bf16(wkf[ks], a, acck[m], 0, 0, 0);
                    accv[m] = __builtin_amdgcn_mfma_f32_16x16x32_bf16(a, wvf[ks], accv[m], 0, 0, 0);
                }
            }
        }
        #pragma unroll
        for (int m = 0; m < 2; ++m) {
            int T = th * 2 + m;
            bf16x4 pq, pk, pv;
            #pragma unroll
            for (int r = 0; r < 4; ++r) {
                pq[r] = (bf16_t)(accq[m][r] + qb4[r]);          // dim = dt*16+quad*4+r
                pk[r] = (bf16_t)(acck[m][r] + kb4[r]);
                int tok = T * 16 + quad * 4 + r;
                pv[r] = (tok < 49) ? (bf16_t)(accv[m][r] + bvs) : (bf16_t)0.0f;
            }
            *(bf16x4*)&sQ [(T * 16 + l15) * QP + dt * 16 + quad * 4] = pq;
            *(bf16x4*)&sK [(T * 16 + l15) * QP + dt * 16 + quad * 4] = pk;
            *(bf16x4*)&sVT[(dt * 16 + l15) * VP + T * 16 + quad * 4] = pv;
        }
        __syncthreads();   // q/k/v visible; sX elems [0,9216) free for sP overlay

        // ---- attention: wave = (token-tile dt, head-slice th) ----
        const int hc = th * 32;
        bf16_t* sP = &sX[wv * 16 * PP];   // wave-private [16 q][PP k]
        bf16x8 aq = *(const bf16x8*)&sQ[(dt * 16 + l15) * QP + hc + quad * 8];
        f32x4 sc[4];
        #pragma unroll
        for (int tj = 0; tj < 4; ++tj) {
            bf16x8 kf = *(const bf16x8*)&sK[(tj * 16 + l15) * QP + hc + quad * 8];
            f32x4 z = {0.f, 0.f, 0.f, 0.f};
            sc[tj] = __builtin_amdgcn_mfma_f32_16x16x32_bf16(kf, aq, z, 0, 0, 0);
        }
        // S^T layout: lane holds S[k=tj*16+quad*4+r][q=dt*16+l15]
        // no max-subtraction: |logit| <~ 2.5 -> exp2 can't overflow
        #pragma unroll
        for (int tj = 0; tj < 3; ++tj) {
            bf16x4 pp;
            #pragma unroll
            for (int r = 0; r < 4; ++r)
                pp[r] = (bf16_t)__builtin_amdgcn_exp2f(sc[tj][r] * SCL);
            *(bf16x4*)&sP[l15 * PP + tj * 16 + quad * 4] = pp;
        }
        {   // tj=3: only k=48 real; zeros for k=49..63
            bf16x4 pp;
            pp[0] = (quad == 0) ? (bf16_t)__builtin_amdgcn_exp2f(sc[3][0] * SCL) : (bf16_t)0.0f;
            pp[1] = (bf16_t)0.0f; pp[2] = (bf16_t)0.0f; pp[3] = (bf16_t)0.0f;
            *(bf16x4*)&sP[l15 * PP + 48 + quad * 4] = pp;
        }
        // O' = P V; row sums via ones-MFMA
        f32x4 o0 = {0.f,0.f,0.f,0.f}, o1 = {0.f,0.f,0.f,0.f}, lsum = {0.f,0.f,0.f,0.f};
        #pragma unroll
        for (int ks = 0; ks < 2; ++ks) {
            bf16x8 ap = *(const bf16x8*)&sP[l15 * PP + ks * 32 + quad * 8];
            bf16x8 b0 = *(const bf16x8*)&sVT[(hc + l15) * VP + ks * 32 + quad * 8];
            bf16x8 b1 = *(const bf16x8*)&sVT[(hc + 16 + l15) * VP + ks * 32 + quad * 8];
            o0   = __builtin_amdgcn_mfma_f32_16x16x32_bf16(ap, b0,   o0,   0, 0, 0);
            o1   = __builtin_amdgcn_mfma_f32_16x16x32_bf16(ap, b1,   o1,   0, 0, 0);
            lsum = __builtin_amdgcn_mfma_f32_16x16x32_bf16(ap, vone, lsum, 0, 0, 0);
        }
        const int h = g * 2 + th;
        #pragma unroll
        for (int r = 0; r < 4; ++r) {
            int t = dt * 16 + quad * 4 + r;
            if (t < 49) {
                float rinv = __builtin_amdgcn_rcpf(lsum[r]);   // normalize after PV (linear)
                long off = (long)(win * 49 + t) * 256 + h * 32 + l15;
                out[off]      = o0[r] * rinv;
                out[off + 16] = o1[r] * rinv;
            }
        }
        __syncthreads();   // attn done reading sQ/sK/sVT and sP

        if (g < 3) {
            // restore sX rows 0..35 (covers the 9216-elem sP overlay) from registers
            {
                int row = tid >> 5, cv = tid & 31;
                *(bf16x8*)&sX[row * XP + cv * 8] = xreg[0];            // rows 0..15
            }
            {
                int row = 16 + (tid >> 5), cv = tid & 31;
                *(bf16x8*)&sX[row * XP + cv * 8] = xreg[1];            // rows 16..31
            }
            if (tid < 128) {
                int row = 32 + (tid >> 5), cv = tid & 31;
                *(bf16x8*)&sX[row * XP + cv * 8] = xreg[2];            // rows 32..35
            }
            __syncthreads();   // sX restored before next projection reads it
        }
    }
}

extern "C" void kernel_launch(void* const* d_in, const int* in_sizes, int n_in,
                              void* d_out, int out_size, void* d_ws, size_t ws_size,
                              hipStream_t stream) {
    const float* x  = (const float*)d_in[0];
    const float* Wq = (const float*)d_in[1];
    const float* bq = (const float*)d_in[2];
    const float* Wk = (const float*)d_in[3];
    const float* bk = (const float*)d_in[4];
    const float* Wv = (const float*)d_in[5];
    const float* bv = (const float*)d_in[6];
    float* out = (float*)d_out;
    bf16_t* Wb = (bf16_t*)d_ws;    // 393216 B of ws
    (void)in_sizes; (void)n_in; (void)out_size; (void)ws_size;

    hipLaunchKernelGGL(wcvt_kernel, dim3(96), dim3(256), 0, stream, Wq, Wk, Wv, Wb);
    hipLaunchKernelGGL(swin_win_attn, dim3(2048), dim3(512), 0, stream,
                       x, Wb, bq, bk, bv, out);
}

// Round 3
// 270.306 us; speedup vs baseline: 1.2900x; 1.2900x over previous
//
#include <hip/hip_runtime.h>
#include <hip/hip_bf16.h>

typedef __bf16 bf16_t;
typedef __bf16 bf16x4 __attribute__((ext_vector_type(4)));
typedef __bf16 bf16x8 __attribute__((ext_vector_type(8)));
typedef float  f32x4  __attribute__((ext_vector_type(4)));

#define XP 264          // sX row pitch (elems); 528 B rows
#define QP 72           // q/k row pitch (64 cols + 8 pad)
#define VP 72
#define PP 72
#define SCL 0.09016844f // (1/16) * log2(e): softmax scale folded into exp2

__device__ inline bf16x8 cvt8(f32x4 a, f32x4 b) {
    bf16x8 r;
    r[0]=(bf16_t)a[0]; r[1]=(bf16_t)a[1]; r[2]=(bf16_t)a[2]; r[3]=(bf16_t)a[3];
    r[4]=(bf16_t)b[0]; r[5]=(bf16_t)b[1]; r[6]=(bf16_t)b[2]; r[7]=(bf16_t)b[3];
    return r;
}

// Prep: W{q,k,v} fp32 [256x256] -> bf16 into ws ([3][256][256]). 96 blocks x 256 thr.
__global__ __launch_bounds__(256)
void wcvt_kernel(const float* __restrict__ Wq, const float* __restrict__ Wk,
                 const float* __restrict__ Wv, bf16_t* __restrict__ o)
{
    int e = (blockIdx.x * 256 + threadIdx.x) * 8;
    const float* src = (e < 65536) ? (Wq + e)
                     : (e < 131072 ? (Wk + (e - 65536)) : (Wv + (e - 131072)));
    f32x4 f0 = *(const f32x4*)src;
    f32x4 f1 = *(const f32x4*)(src + 4);
    *(bf16x8*)(o + e) = cvt8(f0, f1);
}

// R0 skeleton: one block = one (window, head-pair group). 4 waves, 2 barriers,
// grid 8192, all 24 weight fragments preloaded into registers BEFORE the barrier.
// New vs R0: (1) fused QKV - each X-fragment ds_read feeds 3 MFMAs (proj A-reads
// 96->32/wave): X frag (token=l15, k=quad*8..) is simultaneously a valid
// B-operand for Q/K = mfma(W, X) and A-operand for V = mfma(X, W).
// (2) operand-swapped outputs make all stores contiguous b64:
//     Q/K: D=[dim][token] -> 4 acc elems = 4 dims -> b64 into sQ[tok][dim]
//     V:   D=[token][dim] -> 4 acc elems = 4 toks -> b64 into sVT[dim][tok]
//     S^T = mfma(K, Q): 4 acc elems = 4 k-toks -> b64 into sP[q][k]
// LDS: sX 25872 + sQ 9216 + sK 9216 + sVT 9216 = 53520 B -> 3 blocks/CU.
// X-frag reads of virtual token rows 49..63 spill into the sQ region (garbage,
// possibly NaN bf16) - they only pollute outputs for tokens t>=49, never stored;
// sVT cols >=49 and sP cols >=49 forced to exact 0 so garbage can't cross rows.
__global__ __launch_bounds__(256, 3)
void swin_win_attn(const float* __restrict__ x,
                   const bf16_t* __restrict__ Wb,      // ws: [3][256][256] bf16
                   const float* __restrict__ bq, const float* __restrict__ bk,
                   const float* __restrict__ bv,
                   float* __restrict__ out)
{
    __shared__ __attribute__((aligned(16))) bf16_t smem[49 * XP + 2 * 64 * QP + 64 * VP];
    bf16_t* sX  = smem;                 // [49 real rows][XP]; rows 0..17 reused as sP
    bf16_t* sQ  = smem + 49 * XP;       // [64 tok][QP dims]
    bf16_t* sK  = sQ + 64 * QP;         // [64 tok][QP dims]
    bf16_t* sVT = sK + 64 * QP;         // [64 dim][VP toks]

    const int tid  = threadIdx.x;
    const int wv   = tid >> 6;
    const int lane = tid & 63;
    const int l15  = lane & 15;
    const int quad = lane >> 4;

    // XCD swizzle: the 4 group-blocks of a window share bid%8
    const int bid = blockIdx.x;                      // 0..8191
    const int win = ((bid >> 5) << 3) | (bid & 7);   // 0..2047
    const int g   = (bid >> 3) & 3;                  // head-pair group

    const int b  = win >> 6;
    const int w  = win & 63;
    const int wy = w >> 3;
    const int wx = w & 7;
    const float* xw = x + (((b * 56) + wy * 7) * 56 + wx * 7) * 256;

    // ---- stage x (fp32 -> bf16): issue ALL loads, then all LDS writes ----
    f32x4 la[7], lb[7];
    #pragma unroll
    for (int k = 0; k < 6; ++k) {
        int idx = k * 256 + tid, row = idx >> 5, cv = idx & 31;
        int ty = row / 7, tx = row - ty * 7;
        const float* src = xw + (ty * 56 + tx) * 256 + cv * 8;
        la[k] = *(const f32x4*)src;
        lb[k] = *(const f32x4*)(src + 4);
    }
    if (tid < 32) {
        const float* src = xw + (6 * 56 + 6) * 256 + tid * 8;   // row 48
        la[6] = *(const f32x4*)src;
        lb[6] = *(const f32x4*)(src + 4);
    }
    #pragma unroll
    for (int k = 0; k < 6; ++k) {
        int idx = k * 256 + tid, row = idx >> 5, cv = idx & 31;
        *(bf16x8*)&sX[row * XP + cv * 8] = cvt8(la[k], lb[k]);
    }
    if (tid < 32)
        *(bf16x8*)&sX[48 * XP + tid * 8] = cvt8(la[6], lb[6]);

    // ---- preload ALL weight fragments + biases (no LDS dep; overlaps barrier) ----
    const int dglob = g * 64 + wv * 16 + l15;        // this lane's weight row (dim)
    const bf16_t* wbase = Wb + dglob * 256 + quad * 8;
    bf16x8 wq[8], wk[8], wvv[8];
    #pragma unroll
    for (int ks = 0; ks < 8; ++ks) {
        wq [ks] = *(const bf16x8*)(wbase + ks * 32);
        wk [ks] = *(const bf16x8*)(wbase + 65536 + ks * 32);
        wvv[ks] = *(const bf16x8*)(wbase + 131072 + ks * 32);
    }
    f32x4 qb4 = *(const f32x4*)&bq[g * 64 + wv * 16 + quad * 4];
    f32x4 kb4 = *(const f32x4*)&bk[g * 64 + wv * 16 + quad * 4];
    const float bvs = bv[dglob];
    __syncthreads();

    // ---- fused QKV projection: 32 X-frag reads, 96 MFMAs per wave ----
    f32x4 accq[4], acck[4], accv[4];
    #pragma unroll
    for (int mt = 0; mt < 4; ++mt) {
        accq[mt] = f32x4{0.f,0.f,0.f,0.f};
        acck[mt] = f32x4{0.f,0.f,0.f,0.f};
        accv[mt] = f32x4{0.f,0.f,0.f,0.f};
    }
    #pragma unroll
    for (int ks = 0; ks < 8; ++ks) {
        #pragma unroll
        for (int mt = 0; mt < 4; ++mt) {
            bf16x8 a = *(const bf16x8*)&sX[(mt * 16 + l15) * XP + ks * 32 + quad * 8];
            accq[mt] = __builtin_amdgcn_mfma_f32_16x16x32_bf16(wq [ks], a, accq[mt], 0, 0, 0);
            acck[mt] = __builtin_amdgcn_mfma_f32_16x16x32_bf16(wk [ks], a, acck[mt], 0, 0, 0);
            accv[mt] = __builtin_amdgcn_mfma_f32_16x16x32_bf16(a, wvv[ks], accv[mt], 0, 0, 0);
        }
    }
    #pragma unroll
    for (int mt = 0; mt < 4; ++mt) {
        bf16x4 pq, pk, pv;
        #pragma unroll
        for (int r = 0; r < 4; ++r) {
            pq[r] = (bf16_t)(accq[mt][r] + qb4[r]);     // dim = wv*16+quad*4+r
            pk[r] = (bf16_t)(acck[mt][r] + kb4[r]);
            int tok = mt * 16 + quad * 4 + r;
            pv[r] = (tok < 49) ? (bf16_t)(accv[mt][r] + bvs) : (bf16_t)0.0f;
        }
        *(bf16x4*)&sQ [(mt * 16 + l15) * QP + wv * 16 + quad * 4] = pq;
        *(bf16x4*)&sK [(mt * 16 + l15) * QP + wv * 16 + quad * 4] = pk;
        *(bf16x4*)&sVT[(wv * 16 + l15) * VP + mt * 16 + quad * 4] = pv;
    }
    __syncthreads();   // q/k/v visible; sX dead -> sP overlay safe

    // ---- attention: wave wv owns token rows [wv*16, wv*16+16); no barriers ----
    bf16_t* sP = &sX[wv * 16 * PP];   // wave-private unnormalized-P tile [16 q][PP k]
    bf16x8 vone;
    #pragma unroll
    for (int j = 0; j < 8; ++j) vone[j] = (bf16_t)1.0f;

    #pragma unroll
    for (int hs = 0; hs < 2; ++hs) {
        const int hc = hs * 32;
        bf16x8 aq = *(const bf16x8*)&sQ[(wv * 16 + l15) * QP + hc + quad * 8];
        f32x4 sc[4];
        #pragma unroll
        for (int tj = 0; tj < 4; ++tj) {
            bf16x8 kf = *(const bf16x8*)&sK[(tj * 16 + l15) * QP + hc + quad * 8];
            f32x4 z = {0.f, 0.f, 0.f, 0.f};
            sc[tj] = __builtin_amdgcn_mfma_f32_16x16x32_bf16(kf, aq, z, 0, 0, 0);
        }
        // S^T layout: lane holds S[k=tj*16+quad*4+r][q=wv*16+l15]
        // no max-subtraction: |logit| <~ 2.5 (S ~ N(0,32), /16) -> exp2 can't overflow
        #pragma unroll
        for (int tj = 0; tj < 3; ++tj) {
            bf16x4 pp;
            #pragma unroll
            for (int r = 0; r < 4; ++r)
                pp[r] = (bf16_t)__builtin_amdgcn_exp2f(sc[tj][r] * SCL);
            *(bf16x4*)&sP[l15 * PP + tj * 16 + quad * 4] = pp;
        }
        {   // tj=3: only k=48 real; exact zeros for k=49..63
            bf16x4 pp;
            pp[0] = (quad == 0) ? (bf16_t)__builtin_amdgcn_exp2f(sc[3][0] * SCL) : (bf16_t)0.0f;
            pp[1] = (bf16_t)0.0f; pp[2] = (bf16_t)0.0f; pp[3] = (bf16_t)0.0f;
            *(bf16x4*)&sP[l15 * PP + 48 + quad * 4] = pp;
        }
        // O' = P V; row sums via ones-MFMA (every output col = sum_j P[i][j])
        f32x4 o0 = {0.f,0.f,0.f,0.f}, o1 = {0.f,0.f,0.f,0.f}, lsum = {0.f,0.f,0.f,0.f};
        #pragma unroll
        for (int ks = 0; ks < 2; ++ks) {
            bf16x8 ap = *(const bf16x8*)&sP[l15 * PP + ks * 32 + quad * 8];
            bf16x8 b0 = *(const bf16x8*)&sVT[(hc + l15) * VP + ks * 32 + quad * 8];
            bf16x8 b1 = *(const bf16x8*)&sVT[(hc + 16 + l15) * VP + ks * 32 + quad * 8];
            o0   = __builtin_amdgcn_mfma_f32_16x16x32_bf16(ap, b0,   o0,   0, 0, 0);
            o1   = __builtin_amdgcn_mfma_f32_16x16x32_bf16(ap, b1,   o1,   0, 0, 0);
            lsum = __builtin_amdgcn_mfma_f32_16x16x32_bf16(ap, vone, lsum, 0, 0, 0);
        }
        const int h = g * 2 + hs;
        #pragma unroll
        for (int r = 0; r < 4; ++r) {
            int t = wv * 16 + quad * 4 + r;
            if (t < 49) {
                float rinv = __builtin_amdgcn_rcpf(lsum[r]);   // normalize after PV (linear)
                long off = (long)(win * 49 + t) * 256 + h * 32 + l15;
                out[off]      = o0[r] * rinv;
                out[off + 16] = o1[r] * rinv;
            }
        }
    }
}

extern "C" void kernel_launch(void* const* d_in, const int* in_sizes, int n_in,
                              void* d_out, int out_size, void* d_ws, size_t ws_size,
                              hipStream_t stream) {
    const float* x  = (const float*)d_in[0];
    const float* Wq = (const float*)d_in[1];
    const float* bq = (const float*)d_in[2];
    const float* Wk = (const float*)d_in[3];
    const float* bk = (const float*)d_in[4];
    const float* Wv = (const float*)d_in[5];
    const float* bv = (const float*)d_in[6];
    float* out = (float*)d_out;
    bf16_t* Wb = (bf16_t*)d_ws;    // 393216 B of ws
    (void)in_sizes; (void)n_in; (void)out_size; (void)ws_size;

    hipLaunchKernelGGL(wcvt_kernel, dim3(96), dim3(256), 0, stream, Wq, Wk, Wv, Wb);
    hipLaunchKernelGGL(swin_win_attn, dim3(8192), dim3(256), 0, stream,
                       x, Wb, bq, bk, bv, out);
}